// Round 1
// baseline (643.921 us; speedup 1.0000x reference)
//
#include <hip/hip_runtime.h>
#include <cstdint>
#include <cstddef>

typedef __bf16 bf16x8 __attribute__((ext_vector_type(8)));
typedef float f32x4 __attribute__((ext_vector_type(4)));

__device__ __forceinline__ uint16_t f2bf(float f) {
    union { float f; uint32_t u; } v; v.f = f;
    uint32_t r = (v.u + 0x7fffu + ((v.u >> 16) & 1u)) >> 16;
    return (uint16_t)r;
}
__device__ __forceinline__ float bf2f(uint16_t h) {
    union { uint32_t u; float f; } v; v.u = ((uint32_t)h) << 16;
    return v.f;
}

// ---------------------------------------------------------------------------
// Weight transpose + convert: W (R x C, fp32) -> Wt (C x R, bf16)
// ---------------------------------------------------------------------------
__global__ __launch_bounds__(256) void k_transpose_w(const float* __restrict__ W,
                                                     uint16_t* __restrict__ Wt,
                                                     int R, int C) {
    __shared__ uint16_t tile[32][33];
    int c0 = blockIdx.x * 32;
    int r0 = blockIdx.y * 32;
    int t = threadIdx.x;
    int tc = t & 31, tr = t >> 5;
#pragma unroll
    for (int i = 0; i < 4; ++i) {
        int r = tr * 4 + i;
        tile[r][tc] = f2bf(W[(size_t)(r0 + r) * C + c0 + tc]);
    }
    __syncthreads();
#pragma unroll
    for (int i = 0; i < 4; ++i) {
        int c = tr * 4 + i;
        Wt[(size_t)(c0 + c) * R + r0 + tc] = tile[tc][c];
    }
}

// ---------------------------------------------------------------------------
// V transpose: V (2048 x 512 bf16) -> Vt (4 x 128 x 2048 bf16)
// ---------------------------------------------------------------------------
__global__ __launch_bounds__(256) void k_transpose_v(const uint16_t* __restrict__ V,
                                                     uint16_t* __restrict__ Vt) {
    __shared__ uint16_t tile[32][33];
    int c0 = blockIdx.x * 32;   // column within 512
    int s0 = blockIdx.y * 32;   // sequence position
    int t = threadIdx.x;
    int tc = t & 31, tr = t >> 5;
#pragma unroll
    for (int i = 0; i < 4; ++i) {
        int s = tr * 4 + i;
        tile[s][tc] = V[(size_t)(s0 + s) * 512 + c0 + tc];
    }
    __syncthreads();
#pragma unroll
    for (int i = 0; i < 4; ++i) {
        int c = c0 + tr * 4 + i;   // global col = kvh*128 + d
        Vt[(size_t)c * 2048 + s0 + tc] = tile[tc][tr * 4 + i];
    }
}

// ---------------------------------------------------------------------------
// RoPE in place on Q (2048x3584) and K (2048x512); Q also scaled by 1/sqrt(128)
// ---------------------------------------------------------------------------
__global__ __launch_bounds__(256) void k_rope(uint16_t* __restrict__ Q,
                                              uint16_t* __restrict__ K,
                                              const int* __restrict__ pos_ids) {
    int idx = blockIdx.x * 256 + threadIdx.x;   // 2048*64 threads
    int d = idx & 63;
    int s = idx >> 6;
    float pos = (float)pos_ids[s];
    // inv_freq = 1e6 ^ (-d/64);  log2(1e6) = 19.9315685693
    float ang = pos * exp2f((float)d * (-19.931568569324174f / 64.0f));
    float cs = cosf(ang), sn = sinf(ang);
    const float qscale = 0.08838834764831845f;   // 1/sqrt(128)
    uint16_t* q = Q + (size_t)s * 3584 + d;
#pragma unroll
    for (int h = 0; h < 28; ++h) {
        float x1 = bf2f(q[h * 128]);
        float x2 = bf2f(q[h * 128 + 64]);
        q[h * 128]      = f2bf((x1 * cs - x2 * sn) * qscale);
        q[h * 128 + 64] = f2bf((x2 * cs + x1 * sn) * qscale);
    }
    uint16_t* k = K + (size_t)s * 512 + d;
#pragma unroll
    for (int h = 0; h < 4; ++h) {
        float x1 = bf2f(k[h * 128]);
        float x2 = bf2f(k[h * 128 + 64]);
        k[h * 128]      = f2bf(x1 * cs - x2 * sn);
        k[h * 128 + 64] = f2bf(x2 * cs + x1 * sn);
    }
}

// ---------------------------------------------------------------------------
// Fused QKV GEMM: X (2048x3584 fp32) @ [Wq|Wk|Wv] -> Q,K,V (bf16)
// B inputs are pre-transposed bf16 (N x K). 128x128x32 tiles, 4 waves 2x2.
// ---------------------------------------------------------------------------
#define GLD 40   // padded LDS stride (bf16 elems): 80B, 16B-aligned, even banks

__global__ __launch_bounds__(256) void k_gemm_qkv(
    const float* __restrict__ X,        // 2048 x 3584
    const uint16_t* __restrict__ WqT,   // 3584 x 3584
    const uint16_t* __restrict__ WkT,   // 512 x 3584
    const uint16_t* __restrict__ WvT,   // 512 x 3584
    uint16_t* __restrict__ Q,           // 2048 x 3584
    uint16_t* __restrict__ K,           // 2048 x 512
    uint16_t* __restrict__ V)           // 2048 x 512
{
    __shared__ uint16_t Als[128 * GLD];
    __shared__ uint16_t Bls[128 * GLD];

    int nt = blockIdx.x;        // 0..35
    int m0 = blockIdx.y * 128;

    const uint16_t* Bt; uint16_t* dst; int dstStride; int colBase;
    if (nt < 28)      { Bt = WqT + (size_t)nt * 128 * 3584;        dst = Q; dstStride = 3584; colBase = nt * 128; }
    else if (nt < 32) { Bt = WkT + (size_t)(nt - 28) * 128 * 3584; dst = K; dstStride = 512;  colBase = (nt - 28) * 128; }
    else              { Bt = WvT + (size_t)(nt - 32) * 128 * 3584; dst = V; dstStride = 512;  colBase = (nt - 32) * 128; }

    int tid = threadIdx.x;
    int w = tid >> 6, lane = tid & 63, quad = lane >> 4, l15 = lane & 15;
    int wm = (w >> 1) * 64, wn = (w & 1) * 64;

    f32x4 acc[4][4] = {};

    int srow = tid >> 1;
    int sseg = (tid & 1) * 16;

    for (int k0 = 0; k0 < 3584; k0 += 32) {
        __syncthreads();
        // stage A: fp32 -> bf16
        {
            const float* src = X + (size_t)(m0 + srow) * 3584 + k0 + sseg;
#pragma unroll
            for (int i = 0; i < 2; ++i) {
                f32x4 v0 = *reinterpret_cast<const f32x4*>(src + i * 8);
                f32x4 v1 = *reinterpret_cast<const f32x4*>(src + i * 8 + 4);
                uint4 wv;
                wv.x = (uint32_t)f2bf(v0[0]) | ((uint32_t)f2bf(v0[1]) << 16);
                wv.y = (uint32_t)f2bf(v0[2]) | ((uint32_t)f2bf(v0[3]) << 16);
                wv.z = (uint32_t)f2bf(v1[0]) | ((uint32_t)f2bf(v1[1]) << 16);
                wv.w = (uint32_t)f2bf(v1[2]) | ((uint32_t)f2bf(v1[3]) << 16);
                *reinterpret_cast<uint4*>(&Als[srow * GLD + sseg + i * 8]) = wv;
            }
        }
        // stage B: bf16 passthrough
        {
            const uint16_t* src = Bt + (size_t)srow * 3584 + k0 + sseg;
#pragma unroll
            for (int i = 0; i < 2; ++i)
                *reinterpret_cast<uint4*>(&Bls[srow * GLD + sseg + i * 8]) =
                    *reinterpret_cast<const uint4*>(src + i * 8);
        }
        __syncthreads();

        bf16x8 af[4], bfr[4];
#pragma unroll
        for (int i = 0; i < 4; ++i)
            af[i] = *reinterpret_cast<const bf16x8*>(&Als[(wm + i * 16 + l15) * GLD + quad * 8]);
#pragma unroll
        for (int j = 0; j < 4; ++j)
            bfr[j] = *reinterpret_cast<const bf16x8*>(&Bls[(wn + j * 16 + l15) * GLD + quad * 8]);
#pragma unroll
        for (int i = 0; i < 4; ++i)
#pragma unroll
            for (int j = 0; j < 4; ++j)
                acc[i][j] = __builtin_amdgcn_mfma_f32_16x16x32_bf16(af[i], bfr[j], acc[i][j], 0, 0, 0);
    }

    // epilogue: C/D layout row = quad*4+reg, col = lane&15
#pragma unroll
    for (int i = 0; i < 4; ++i)
#pragma unroll
        for (int r = 0; r < 4; ++r) {
            int grow = m0 + wm + i * 16 + quad * 4 + r;
#pragma unroll
            for (int j = 0; j < 4; ++j) {
                int gcol = colBase + wn + j * 16 + l15;
                dst[(size_t)grow * dstStride + gcol] = f2bf(acc[i][j][r]);
            }
        }
}

// ---------------------------------------------------------------------------
// Output GEMM: attn (2048x3584 bf16) @ Wo -> out (2048x3584 fp32)
// ---------------------------------------------------------------------------
__global__ __launch_bounds__(256) void k_gemm_o(
    const uint16_t* __restrict__ A,     // 2048 x 3584 bf16
    const uint16_t* __restrict__ WoT,   // 3584 x 3584 bf16 (N x K)
    float* __restrict__ out)            // 2048 x 3584 fp32
{
    __shared__ uint16_t Als[128 * GLD];
    __shared__ uint16_t Bls[128 * GLD];

    int nt = blockIdx.x;        // 0..27
    int m0 = blockIdx.y * 128;
    const uint16_t* Bt = WoT + (size_t)nt * 128 * 3584;

    int tid = threadIdx.x;
    int w = tid >> 6, lane = tid & 63, quad = lane >> 4, l15 = lane & 15;
    int wm = (w >> 1) * 64, wn = (w & 1) * 64;

    f32x4 acc[4][4] = {};

    int srow = tid >> 1;
    int sseg = (tid & 1) * 16;

    for (int k0 = 0; k0 < 3584; k0 += 32) {
        __syncthreads();
        {
            const uint16_t* src = A + (size_t)(m0 + srow) * 3584 + k0 + sseg;
#pragma unroll
            for (int i = 0; i < 2; ++i)
                *reinterpret_cast<uint4*>(&Als[srow * GLD + sseg + i * 8]) =
                    *reinterpret_cast<const uint4*>(src + i * 8);
        }
        {
            const uint16_t* src = Bt + (size_t)srow * 3584 + k0 + sseg;
#pragma unroll
            for (int i = 0; i < 2; ++i)
                *reinterpret_cast<uint4*>(&Bls[srow * GLD + sseg + i * 8]) =
                    *reinterpret_cast<const uint4*>(src + i * 8);
        }
        __syncthreads();

        bf16x8 af[4], bfr[4];
#pragma unroll
        for (int i = 0; i < 4; ++i)
            af[i] = *reinterpret_cast<const bf16x8*>(&Als[(wm + i * 16 + l15) * GLD + quad * 8]);
#pragma unroll
        for (int j = 0; j < 4; ++j)
            bfr[j] = *reinterpret_cast<const bf16x8*>(&Bls[(wn + j * 16 + l15) * GLD + quad * 8]);
#pragma unroll
        for (int i = 0; i < 4; ++i)
#pragma unroll
            for (int j = 0; j < 4; ++j)
                acc[i][j] = __builtin_amdgcn_mfma_f32_16x16x32_bf16(af[i], bfr[j], acc[i][j], 0, 0, 0);
    }

#pragma unroll
    for (int i = 0; i < 4; ++i)
#pragma unroll
        for (int r = 0; r < 4; ++r) {
            int grow = m0 + wm + i * 16 + quad * 4 + r;
#pragma unroll
            for (int j = 0; j < 4; ++j) {
                int gcol = nt * 128 + wn + j * 16 + l15;
                out[(size_t)grow * 3584 + gcol] = acc[i][j][r];
            }
        }
}

// ---------------------------------------------------------------------------
// Causal GQA flash attention.
// Block = (qt, h): 64 q rows, 4 waves x 16 rows. K-tiles of 64 keys.
// ---------------------------------------------------------------------------
#define KLD 136   // 64 x 136 bf16  (272B rows: 16B-aligned, even banks)
#define VLD 72    // 128 x 72 bf16  (144B rows)
#define PLD 72    // 16 x 72 bf16 per wave

__global__ __launch_bounds__(256) void k_flash(
    const uint16_t* __restrict__ Q,    // 2048x3584 (roped, pre-scaled)
    const uint16_t* __restrict__ K,    // 2048x512  (roped)
    const uint16_t* __restrict__ Vt,   // 4x128x2048
    uint16_t* __restrict__ O)          // 2048x3584
{
    __shared__ uint16_t Kls[64 * KLD];
    __shared__ uint16_t Vls[128 * VLD];
    __shared__ uint16_t Pls[4][16 * PLD];

    int qt = blockIdx.x;    // 0..31
    int h  = blockIdx.y;    // 0..27
    int kvh = h / 7;
    int tid = threadIdx.x;
    int w = tid >> 6, lane = tid & 63, quad = lane >> 4, l15 = lane & 15;
    int q0 = qt * 64;

    // Q fragments (A-operand: lane holds A[m=lane&15][k=quad*8+j])
    bf16x8 qf[4];
    {
        const uint16_t* qptr = Q + (size_t)(q0 + w * 16 + l15) * 3584 + h * 128 + quad * 8;
#pragma unroll
        for (int c = 0; c < 4; ++c)
            qf[c] = *reinterpret_cast<const bf16x8*>(qptr + c * 32);
    }

    f32x4 acc[8] = {};
    float m_i[4], l_i[4];
#pragma unroll
    for (int r = 0; r < 4; ++r) { m_i[r] = -1e30f; l_i[r] = 0.f; }

    for (int kt = 0; kt <= qt; ++kt) {
        // stage K tile: 64 keys x 128 d
        {
            int row = tid >> 2;
            int cb = (tid & 3) * 32;
            const uint16_t* src = K + (size_t)(kt * 64 + row) * 512 + kvh * 128 + cb;
            uint16_t* d = &Kls[row * KLD + cb];
#pragma unroll
            for (int i = 0; i < 4; ++i)
                *reinterpret_cast<uint4*>(d + i * 8) = *reinterpret_cast<const uint4*>(src + i * 8);
        }
        // stage Vt tile: 128 d x 64 keys
        {
            int dr = tid >> 1;
            int sb = (tid & 1) * 32;
            const uint16_t* src = Vt + (size_t)kvh * 128 * 2048 + (size_t)dr * 2048 + kt * 64 + sb;
            uint16_t* d = &Vls[dr * VLD + sb];
#pragma unroll
            for (int i = 0; i < 4; ++i)
                *reinterpret_cast<uint4*>(d + i * 8) = *reinterpret_cast<const uint4*>(src + i * 8);
        }
        __syncthreads();

        // QK^T: 16 q x 64 keys per wave
        f32x4 sc[4] = {};
#pragma unroll
        for (int nt = 0; nt < 4; ++nt)
#pragma unroll
            for (int c = 0; c < 4; ++c) {
                bf16x8 kf = *reinterpret_cast<const bf16x8*>(
                    &Kls[(nt * 16 + l15) * KLD + c * 32 + quad * 8]);
                sc[nt] = __builtin_amdgcn_mfma_f32_16x16x32_bf16(qf[c], kf, sc[nt], 0, 0, 0);
            }

        // causal mask on diagonal tile
        if (kt == qt) {
            int qrow = q0 + w * 16 + quad * 4;
#pragma unroll
            for (int nt = 0; nt < 4; ++nt) {
                int key = kt * 64 + nt * 16 + l15;
#pragma unroll
                for (int r = 0; r < 4; ++r)
                    if (key > qrow + r) sc[nt][r] = -1e30f;
            }
        }

        // online softmax (rows = quad*4+r, cols across 16 lanes of the quad)
        float alpha[4];
#pragma unroll
        for (int r = 0; r < 4; ++r) {
            float mx = fmaxf(fmaxf(sc[0][r], sc[1][r]), fmaxf(sc[2][r], sc[3][r]));
#pragma unroll
            for (int off = 8; off >= 1; off >>= 1)
                mx = fmaxf(mx, __shfl_xor(mx, off, 64));
            float mn = fmaxf(m_i[r], mx);
            alpha[r] = __expf(m_i[r] - mn);
            m_i[r] = mn;
        }
        float rs[4] = {0.f, 0.f, 0.f, 0.f};
#pragma unroll
        for (int nt = 0; nt < 4; ++nt)
#pragma unroll
            for (int r = 0; r < 4; ++r) {
                float p = __expf(sc[nt][r] - m_i[r]);
                sc[nt][r] = p;
                rs[r] += p;
            }
#pragma unroll
        for (int r = 0; r < 4; ++r) {
#pragma unroll
            for (int off = 8; off >= 1; off >>= 1)
                rs[r] += __shfl_xor(rs[r], off, 64);
            l_i[r] = l_i[r] * alpha[r] + rs[r];
        }
#pragma unroll
        for (int dt = 0; dt < 8; ++dt)
#pragma unroll
            for (int r = 0; r < 4; ++r)
                acc[dt][r] *= alpha[r];

        // P -> LDS (C-layout out, A-layout in)
        uint16_t* P = Pls[w];
#pragma unroll
        for (int nt = 0; nt < 4; ++nt)
#pragma unroll
            for (int r = 0; r < 4; ++r)
                P[(quad * 4 + r) * PLD + nt * 16 + l15] = f2bf(sc[nt][r]);
        __syncthreads();

        // PV: 16 q x 128 d, reduction over 64 keys (2 chunks of 32)
#pragma unroll
        for (int c = 0; c < 2; ++c) {
            bf16x8 pf = *reinterpret_cast<const bf16x8*>(&P[l15 * PLD + c * 32 + quad * 8]);
#pragma unroll
            for (int dt = 0; dt < 8; ++dt) {
                bf16x8 vf = *reinterpret_cast<const bf16x8*>(
                    &Vls[(dt * 16 + l15) * VLD + c * 32 + quad * 8]);
                acc[dt] = __builtin_amdgcn_mfma_f32_16x16x32_bf16(pf, vf, acc[dt], 0, 0, 0);
            }
        }
        __syncthreads();
    }

    // epilogue
#pragma unroll
    for (int dt = 0; dt < 8; ++dt)
#pragma unroll
        for (int r = 0; r < 4; ++r) {
            float o = acc[dt][r] / l_i[r];
            O[(size_t)(q0 + w * 16 + quad * 4 + r) * 3584 + h * 128 + dt * 16 + l15] = f2bf(o);
        }
}

// ---------------------------------------------------------------------------
extern "C" void kernel_launch(void* const* d_in, const int* in_sizes, int n_in,
                              void* d_out, int out_size, void* d_ws, size_t ws_size,
                              hipStream_t stream) {
    const float* hidden = (const float*)d_in[0];
    const int*   pos    = (const int*)d_in[1];
    const float* Wq     = (const float*)d_in[2];
    const float* Wk     = (const float*)d_in[3];
    const float* Wv     = (const float*)d_in[4];
    const float* Wo     = (const float*)d_in[5];
    float* out = (float*)d_out;

    char* ws = (char*)d_ws;
    size_t o = 0;
    uint16_t* WqT = (uint16_t*)(ws + o); o += (size_t)3584 * 3584 * 2;   // 25690112
    uint16_t* WkT = (uint16_t*)(ws + o); o += (size_t)512  * 3584 * 2;   //  3670016
    uint16_t* WvT = (uint16_t*)(ws + o); o += (size_t)512  * 3584 * 2;
    uint16_t* WoT = (uint16_t*)(ws + o); o += (size_t)3584 * 3584 * 2;
    uint16_t* Qb  = (uint16_t*)(ws + o); o += (size_t)2048 * 3584 * 2;   // 14680064
    uint16_t* Kb  = (uint16_t*)(ws + o); o += (size_t)2048 * 512  * 2;   //  2097152
    uint16_t* Vb  = (uint16_t*)(ws + o); o += (size_t)2048 * 512  * 2;
    uint16_t* Vt  = (uint16_t*)(ws + o); o += (size_t)2048 * 512  * 2;
    uint16_t* At  = (uint16_t*)(ws + o); o += (size_t)2048 * 3584 * 2;
    // total ~94.4 MB

    k_transpose_w<<<dim3(112, 112), 256, 0, stream>>>(Wq, WqT, 3584, 3584);
    k_transpose_w<<<dim3(16, 112),  256, 0, stream>>>(Wk, WkT, 3584, 512);
    k_transpose_w<<<dim3(16, 112),  256, 0, stream>>>(Wv, WvT, 3584, 512);
    k_transpose_w<<<dim3(112, 112), 256, 0, stream>>>(Wo, WoT, 3584, 3584);

    k_gemm_qkv<<<dim3(36, 16), 256, 0, stream>>>(hidden, WqT, WkT, WvT, Qb, Kb, Vb);
    k_rope<<<dim3(512), 256, 0, stream>>>(Qb, Kb, pos);
    k_transpose_v<<<dim3(16, 64), 256, 0, stream>>>(Vb, Vt);
    k_flash<<<dim3(32, 28), 256, 0, stream>>>(Qb, Kb, Vt, At);
    k_gemm_o<<<dim3(28, 16), 256, 0, stream>>>(At, WoT, out);
}

// Round 2
// 543.495 us; speedup vs baseline: 1.1848x; 1.1848x over previous
//
#include <hip/hip_runtime.h>
#include <cstdint>
#include <cstddef>

typedef __bf16 bf16x8 __attribute__((ext_vector_type(8)));
typedef float f32x4 __attribute__((ext_vector_type(4)));

__device__ __forceinline__ uint16_t f2bf(float f) {
    union { float f; uint32_t u; } v; v.f = f;
    uint32_t r = (v.u + 0x7fffu + ((v.u >> 16) & 1u)) >> 16;
    return (uint16_t)r;
}
__device__ __forceinline__ float bf2f(uint16_t h) {
    union { uint32_t u; float f; } v; v.u = ((uint32_t)h) << 16;
    return v.f;
}

// async 16B/lane global->LDS. lds base must be wave-uniform; HW writes lane i
// at base + i*16.
__device__ __forceinline__ void gload_lds16(const void* g, void* l) {
    __builtin_amdgcn_global_load_lds(
        (__attribute__((address_space(1))) void*)g,
        (__attribute__((address_space(3))) void*)l, 16, 0, 0);
}

// ---------------------------------------------------------------------------
// hidden fp32 -> bf16
// ---------------------------------------------------------------------------
__global__ __launch_bounds__(256) void k_tobf16(const float* __restrict__ X,
                                                uint16_t* __restrict__ Y) {
    int i = (blockIdx.x * 256 + threadIdx.x) * 4;
    f32x4 v = *reinterpret_cast<const f32x4*>(X + i);
    uint2 o;
    o.x = (uint32_t)f2bf(v[0]) | ((uint32_t)f2bf(v[1]) << 16);
    o.y = (uint32_t)f2bf(v[2]) | ((uint32_t)f2bf(v[3]) << 16);
    *reinterpret_cast<uint2*>(Y + i) = o;
}

// ---------------------------------------------------------------------------
// Weight transpose + convert: W (R x C, fp32) -> Wt (C x R, bf16)
// ---------------------------------------------------------------------------
__global__ __launch_bounds__(256) void k_transpose_w(const float* __restrict__ W,
                                                     uint16_t* __restrict__ Wt,
                                                     int R, int C) {
    __shared__ uint16_t tile[32][33];
    int c0 = blockIdx.x * 32;
    int r0 = blockIdx.y * 32;
    int t = threadIdx.x;
    int tc = t & 31, tr = t >> 5;
#pragma unroll
    for (int i = 0; i < 4; ++i) {
        int r = tr * 4 + i;
        tile[r][tc] = f2bf(W[(size_t)(r0 + r) * C + c0 + tc]);
    }
    __syncthreads();
#pragma unroll
    for (int i = 0; i < 4; ++i) {
        int c = tr * 4 + i;
        Wt[(size_t)(c0 + c) * R + r0 + tc] = tile[tc][c];
    }
}

// ---------------------------------------------------------------------------
// V transpose: V (2048 x 512 bf16) -> Vt (4 x 128 x 2048 bf16)
// ---------------------------------------------------------------------------
__global__ __launch_bounds__(256) void k_transpose_v(const uint16_t* __restrict__ V,
                                                     uint16_t* __restrict__ Vt) {
    __shared__ uint16_t tile[32][33];
    int c0 = blockIdx.x * 32;
    int s0 = blockIdx.y * 32;
    int t = threadIdx.x;
    int tc = t & 31, tr = t >> 5;
#pragma unroll
    for (int i = 0; i < 4; ++i) {
        int s = tr * 4 + i;
        tile[s][tc] = V[(size_t)(s0 + s) * 512 + c0 + tc];
    }
    __syncthreads();
#pragma unroll
    for (int i = 0; i < 4; ++i) {
        int c = c0 + tr * 4 + i;
        Vt[(size_t)c * 2048 + s0 + tc] = tile[tc][tr * 4 + i];
    }
}

// ---------------------------------------------------------------------------
// RoPE in place. Q additionally scaled by (1/sqrt(128))*log2(e) so flash
// softmax runs in exp2 domain.
// ---------------------------------------------------------------------------
__global__ __launch_bounds__(256) void k_rope(uint16_t* __restrict__ Q,
                                              uint16_t* __restrict__ K,
                                              const int* __restrict__ pos_ids) {
    int idx = blockIdx.x * 256 + threadIdx.x;
    int d = idx & 63;
    int s = idx >> 6;
    float pos = (float)pos_ids[s];
    float ang = pos * exp2f((float)d * (-19.931568569324174f / 64.0f));
    float cs = cosf(ang), sn = sinf(ang);
    const float qscale = 0.08838834764831845f * 1.4426950408889634f;
    uint16_t* q = Q + (size_t)s * 3584 + d;
#pragma unroll
    for (int h = 0; h < 28; ++h) {
        float x1 = bf2f(q[h * 128]);
        float x2 = bf2f(q[h * 128 + 64]);
        q[h * 128]      = f2bf((x1 * cs - x2 * sn) * qscale);
        q[h * 128 + 64] = f2bf((x2 * cs + x1 * sn) * qscale);
    }
    uint16_t* k = K + (size_t)s * 512 + d;
#pragma unroll
    for (int h = 0; h < 4; ++h) {
        float x1 = bf2f(k[h * 128]);
        float x2 = bf2f(k[h * 128 + 64]);
        k[h * 128]      = f2bf(x1 * cs - x2 * sn);
        k[h * 128 + 64] = f2bf(x2 * cs + x1 * sn);
    }
}

// ---------------------------------------------------------------------------
// m97-style GEMM body: A (M x 3584 bf16), Bt (N x 3584 bf16), 128x128 tile,
// BK=32, global_load_lds width-16 staging into unpadded [128][32] LDS.
// ---------------------------------------------------------------------------
#define BK 32

__global__ __launch_bounds__(256) void k_gemm_qkv(
    const uint16_t* __restrict__ A,     // 2048 x 3584 bf16
    const uint16_t* __restrict__ WqT,   // 3584 x 3584
    const uint16_t* __restrict__ WkT,   // 512 x 3584
    const uint16_t* __restrict__ WvT,   // 512 x 3584
    uint16_t* __restrict__ Q,
    uint16_t* __restrict__ K,
    uint16_t* __restrict__ V)
{
    __shared__ uint16_t Als[128 * BK];
    __shared__ uint16_t Bls[128 * BK];

    int nt = blockIdx.x;
    int m0 = blockIdx.y * 128;

    const uint16_t* Bt; uint16_t* dst; int dstStride; int colBase;
    if (nt < 28)      { Bt = WqT + (size_t)nt * 128 * 3584;        dst = Q; dstStride = 3584; colBase = nt * 128; }
    else if (nt < 32) { Bt = WkT + (size_t)(nt - 28) * 128 * 3584; dst = K; dstStride = 512;  colBase = (nt - 28) * 128; }
    else              { Bt = WvT + (size_t)(nt - 32) * 128 * 3584; dst = V; dstStride = 512;  colBase = (nt - 32) * 128; }

    int tid = threadIdx.x;
    int w = tid >> 6, lane = tid & 63, quad = lane >> 4, l15 = lane & 15;
    int wm = (w >> 1) * 64, wn = (w & 1) * 64;

    int lrow = lane >> 2;          // 0..15
    int lcol = (lane & 3) * 8;     // 0,8,16,24

    const uint16_t* aS = A  + (size_t)(m0 + w * 32 + lrow) * 3584 + lcol;
    const uint16_t* bS = Bt + (size_t)(w * 32 + lrow) * 3584 + lcol;
    uint16_t* aD0 = &Als[(w * 32) * BK];
    uint16_t* aD1 = &Als[(w * 32 + 16) * BK];
    uint16_t* bD0 = &Bls[(w * 32) * BK];
    uint16_t* bD1 = &Bls[(w * 32 + 16) * BK];

    f32x4 acc[4][4] = {};

    for (int k0 = 0; k0 < 3584; k0 += BK) {
        __syncthreads();
        gload_lds16(aS + k0, aD0);
        gload_lds16(aS + k0 + (size_t)16 * 3584, aD1);
        gload_lds16(bS + k0, bD0);
        gload_lds16(bS + k0 + (size_t)16 * 3584, bD1);
        __syncthreads();   // drains vmcnt(0): staging complete

        bf16x8 af[4], bfr[4];
#pragma unroll
        for (int i = 0; i < 4; ++i)
            af[i] = *reinterpret_cast<const bf16x8*>(&Als[(wm + i * 16 + l15) * BK + quad * 8]);
#pragma unroll
        for (int j = 0; j < 4; ++j)
            bfr[j] = *reinterpret_cast<const bf16x8*>(&Bls[(wn + j * 16 + l15) * BK + quad * 8]);
#pragma unroll
        for (int i = 0; i < 4; ++i)
#pragma unroll
            for (int j = 0; j < 4; ++j)
                acc[i][j] = __builtin_amdgcn_mfma_f32_16x16x32_bf16(af[i], bfr[j], acc[i][j], 0, 0, 0);
    }

#pragma unroll
    for (int i = 0; i < 4; ++i)
#pragma unroll
        for (int r = 0; r < 4; ++r) {
            int grow = m0 + wm + i * 16 + quad * 4 + r;
#pragma unroll
            for (int j = 0; j < 4; ++j) {
                int gcol = colBase + wn + j * 16 + l15;
                dst[(size_t)grow * dstStride + gcol] = f2bf(acc[i][j][r]);
            }
        }
}

__global__ __launch_bounds__(256) void k_gemm_o(
    const uint16_t* __restrict__ A,     // 2048 x 3584 bf16
    const uint16_t* __restrict__ WoT,   // 3584 x 3584 bf16 (N x K)
    float* __restrict__ out)
{
    __shared__ uint16_t Als[128 * BK];
    __shared__ uint16_t Bls[128 * BK];

    int nt = blockIdx.x;
    int m0 = blockIdx.y * 128;
    const uint16_t* Bt = WoT + (size_t)nt * 128 * 3584;

    int tid = threadIdx.x;
    int w = tid >> 6, lane = tid & 63, quad = lane >> 4, l15 = lane & 15;
    int wm = (w >> 1) * 64, wn = (w & 1) * 64;

    int lrow = lane >> 2;
    int lcol = (lane & 3) * 8;

    const uint16_t* aS = A  + (size_t)(m0 + w * 32 + lrow) * 3584 + lcol;
    const uint16_t* bS = Bt + (size_t)(w * 32 + lrow) * 3584 + lcol;
    uint16_t* aD0 = &Als[(w * 32) * BK];
    uint16_t* aD1 = &Als[(w * 32 + 16) * BK];
    uint16_t* bD0 = &Bls[(w * 32) * BK];
    uint16_t* bD1 = &Bls[(w * 32 + 16) * BK];

    f32x4 acc[4][4] = {};

    for (int k0 = 0; k0 < 3584; k0 += BK) {
        __syncthreads();
        gload_lds16(aS + k0, aD0);
        gload_lds16(aS + k0 + (size_t)16 * 3584, aD1);
        gload_lds16(bS + k0, bD0);
        gload_lds16(bS + k0 + (size_t)16 * 3584, bD1);
        __syncthreads();

        bf16x8 af[4], bfr[4];
#pragma unroll
        for (int i = 0; i < 4; ++i)
            af[i] = *reinterpret_cast<const bf16x8*>(&Als[(wm + i * 16 + l15) * BK + quad * 8]);
#pragma unroll
        for (int j = 0; j < 4; ++j)
            bfr[j] = *reinterpret_cast<const bf16x8*>(&Bls[(wn + j * 16 + l15) * BK + quad * 8]);
#pragma unroll
        for (int i = 0; i < 4; ++i)
#pragma unroll
            for (int j = 0; j < 4; ++j)
                acc[i][j] = __builtin_amdgcn_mfma_f32_16x16x32_bf16(af[i], bfr[j], acc[i][j], 0, 0, 0);
    }

#pragma unroll
    for (int i = 0; i < 4; ++i)
#pragma unroll
        for (int r = 0; r < 4; ++r) {
            int grow = m0 + wm + i * 16 + quad * 4 + r;
#pragma unroll
            for (int j = 0; j < 4; ++j) {
                int gcol = nt * 128 + wn + j * 16 + l15;
                out[(size_t)grow * 3584 + gcol] = acc[i][j][r];
            }
        }
}

// ---------------------------------------------------------------------------
// Flash attention, barrier-free. Wave = 32 q rows (2 x 16), K-tile = 64 keys.
// K/V fragments loaded directly from global (whole KV fits per-XCD L2).
// Per-wave LDS only for the P C->A layout transpose. exp2-domain softmax.
// ---------------------------------------------------------------------------
#define PLD 72

__global__ __launch_bounds__(256, 2) void k_flash(
    const uint16_t* __restrict__ Q,    // 2048x3584 (roped, *1/sqrt(d)*log2e)
    const uint16_t* __restrict__ K,    // 2048x512  (roped)
    const uint16_t* __restrict__ Vt,   // 4x128x2048
    uint16_t* __restrict__ O)          // 2048x3584
{
    __shared__ uint16_t Pls[4][32 * PLD];

    int h  = blockIdx.x;               // 0..27
    int qt = 15 - (int)blockIdx.y;     // heavy blocks dispatched first
    int kvh = h / 7;
    int tid = threadIdx.x;
    int w = tid >> 6, lane = tid & 63, quad = lane >> 4, l15 = lane & 15;
    int q0 = qt * 128 + w * 32;        // this wave's first q row

    const uint16_t* Kh = K + kvh * 128;
    const uint16_t* Vh = Vt + (size_t)kvh * 128 * 2048;
    uint16_t* Pw = &Pls[w][0];

    bf16x8 qf[2][4];
#pragma unroll
    for (int s = 0; s < 2; ++s) {
        const uint16_t* qp = Q + (size_t)(q0 + s * 16 + l15) * 3584 + h * 128 + quad * 8;
#pragma unroll
        for (int c = 0; c < 4; ++c)
            qf[s][c] = *reinterpret_cast<const bf16x8*>(qp + c * 32);
    }

    f32x4 acc[2][8] = {};
    float m_i[2][4], l_i[2][4];
#pragma unroll
    for (int s = 0; s < 2; ++s)
#pragma unroll
        for (int r = 0; r < 4; ++r) { m_i[s][r] = -1e30f; l_i[s][r] = 0.f; }

    int ktmax = (q0 + 31) >> 6;
    for (int kt = 0; kt <= ktmax; ++kt) {
        int kb = kt * 64;
        f32x4 sc[2][4] = {};
        // QK^T: 32 q x 64 keys
#pragma unroll
        for (int nt = 0; nt < 4; ++nt) {
            const uint16_t* kp = Kh + (size_t)(kb + nt * 16 + l15) * 512 + quad * 8;
            bf16x8 kf0 = *reinterpret_cast<const bf16x8*>(kp);
            bf16x8 kf1 = *reinterpret_cast<const bf16x8*>(kp + 32);
            bf16x8 kf2 = *reinterpret_cast<const bf16x8*>(kp + 64);
            bf16x8 kf3 = *reinterpret_cast<const bf16x8*>(kp + 96);
            sc[0][nt] = __builtin_amdgcn_mfma_f32_16x16x32_bf16(qf[0][0], kf0, sc[0][nt], 0, 0, 0);
            sc[0][nt] = __builtin_amdgcn_mfma_f32_16x16x32_bf16(qf[0][1], kf1, sc[0][nt], 0, 0, 0);
            sc[0][nt] = __builtin_amdgcn_mfma_f32_16x16x32_bf16(qf[0][2], kf2, sc[0][nt], 0, 0, 0);
            sc[0][nt] = __builtin_amdgcn_mfma_f32_16x16x32_bf16(qf[0][3], kf3, sc[0][nt], 0, 0, 0);
            sc[1][nt] = __builtin_amdgcn_mfma_f32_16x16x32_bf16(qf[1][0], kf0, sc[1][nt], 0, 0, 0);
            sc[1][nt] = __builtin_amdgcn_mfma_f32_16x16x32_bf16(qf[1][1], kf1, sc[1][nt], 0, 0, 0);
            sc[1][nt] = __builtin_amdgcn_mfma_f32_16x16x32_bf16(qf[1][2], kf2, sc[1][nt], 0, 0, 0);
            sc[1][nt] = __builtin_amdgcn_mfma_f32_16x16x32_bf16(qf[1][3], kf3, sc[1][nt], 0, 0, 0);
        }

        if (kb + 63 > q0) {   // causal mask, wave-uniform trigger
#pragma unroll
            for (int s = 0; s < 2; ++s)
#pragma unroll
                for (int nt = 0; nt < 4; ++nt) {
                    int key = kb + nt * 16 + l15;
#pragma unroll
                    for (int r = 0; r < 4; ++r) {
                        int row = q0 + s * 16 + quad * 4 + r;
                        if (key > row) sc[s][nt][r] = -1e30f;
                    }
                }
        }

        // online softmax (exp2 domain) + P write
#pragma unroll
        for (int s = 0; s < 2; ++s) {
            float alpha[4];
#pragma unroll
            for (int r = 0; r < 4; ++r) {
                float mx = fmaxf(fmaxf(sc[s][0][r], sc[s][1][r]), fmaxf(sc[s][2][r], sc[s][3][r]));
#pragma unroll
                for (int off = 8; off >= 1; off >>= 1)
                    mx = fmaxf(mx, __shfl_xor(mx, off, 64));
                float mn = fmaxf(m_i[s][r], mx);
                alpha[r] = __builtin_amdgcn_exp2f(m_i[s][r] - mn);
                m_i[s][r] = mn;
            }
            float rs[4] = {0.f, 0.f, 0.f, 0.f};
#pragma unroll
            for (int nt = 0; nt < 4; ++nt)
#pragma unroll
                for (int r = 0; r < 4; ++r) {
                    float p = __builtin_amdgcn_exp2f(sc[s][nt][r] - m_i[s][r]);
                    sc[s][nt][r] = p;
                    rs[r] += p;
                }
#pragma unroll
            for (int r = 0; r < 4; ++r) {
#pragma unroll
                for (int off = 8; off >= 1; off >>= 1)
                    rs[r] += __shfl_xor(rs[r], off, 64);
                l_i[s][r] = l_i[s][r] * alpha[r] + rs[r];
            }
#pragma unroll
            for (int dt = 0; dt < 8; ++dt)
#pragma unroll
                for (int r = 0; r < 4; ++r)
                    acc[s][dt][r] *= alpha[r];
#pragma unroll
            for (int nt = 0; nt < 4; ++nt)
#pragma unroll
                for (int r = 0; r < 4; ++r)
                    Pw[(s * 16 + quad * 4 + r) * PLD + nt * 16 + l15] = f2bf(sc[s][nt][r]);
        }

        // PV: 32 q x 128 d (wave-private LDS; in-wave DS ordering, no barrier)
#pragma unroll
        for (int c = 0; c < 2; ++c) {
            bf16x8 pf0 = *reinterpret_cast<const bf16x8*>(&Pw[l15 * PLD + c * 32 + quad * 8]);
            bf16x8 pf1 = *reinterpret_cast<const bf16x8*>(&Pw[(16 + l15) * PLD + c * 32 + quad * 8]);
            const uint16_t* vp = Vh + (size_t)l15 * 2048 + kb + c * 32 + quad * 8;
#pragma unroll
            for (int dt = 0; dt < 8; ++dt) {
                bf16x8 vf = *reinterpret_cast<const bf16x8*>(vp + (size_t)dt * 16 * 2048);
                acc[0][dt] = __builtin_amdgcn_mfma_f32_16x16x32_bf16(pf0, vf, acc[0][dt], 0, 0, 0);
                acc[1][dt] = __builtin_amdgcn_mfma_f32_16x16x32_bf16(pf1, vf, acc[1][dt], 0, 0, 0);
            }
        }
    }

#pragma unroll
    for (int s = 0; s < 2; ++s)
#pragma unroll
        for (int r = 0; r < 4; ++r) {
            float inv = __builtin_amdgcn_rcpf(l_i[s][r]);
            uint16_t* op = O + (size_t)(q0 + s * 16 + quad * 4 + r) * 3584 + h * 128 + l15;
#pragma unroll
            for (int dt = 0; dt < 8; ++dt)
                op[dt * 16] = f2bf(acc[s][dt][r] * inv);
        }
}

// ---------------------------------------------------------------------------
extern "C" void kernel_launch(void* const* d_in, const int* in_sizes, int n_in,
                              void* d_out, int out_size, void* d_ws, size_t ws_size,
                              hipStream_t stream) {
    const float* hidden = (const float*)d_in[0];
    const int*   pos    = (const int*)d_in[1];
    const float* Wq     = (const float*)d_in[2];
    const float* Wk     = (const float*)d_in[3];
    const float* Wv     = (const float*)d_in[4];
    const float* Wo     = (const float*)d_in[5];
    float* out = (float*)d_out;

    char* ws = (char*)d_ws;
    size_t o = 0;
    uint16_t* WqT = (uint16_t*)(ws + o); o += (size_t)3584 * 3584 * 2;
    uint16_t* WkT = (uint16_t*)(ws + o); o += (size_t)512  * 3584 * 2;
    uint16_t* WvT = (uint16_t*)(ws + o); o += (size_t)512  * 3584 * 2;
    uint16_t* WoT = (uint16_t*)(ws + o); o += (size_t)3584 * 3584 * 2;
    uint16_t* Xb  = (uint16_t*)(ws + o); o += (size_t)2048 * 3584 * 2;  // aliased as At after qkv
    uint16_t* Qb  = (uint16_t*)(ws + o); o += (size_t)2048 * 3584 * 2;
    uint16_t* Kb  = (uint16_t*)(ws + o); o += (size_t)2048 * 512  * 2;
    uint16_t* Vb  = (uint16_t*)(ws + o); o += (size_t)2048 * 512  * 2;
    uint16_t* Vt  = (uint16_t*)(ws + o); o += (size_t)2048 * 512  * 2;
    uint16_t* At  = Xb;   // hidden-bf16 is dead once qkv completes

    k_tobf16<<<dim3(7168), 256, 0, stream>>>(hidden, Xb);
    k_transpose_w<<<dim3(112, 112), 256, 0, stream>>>(Wq, WqT, 3584, 3584);
    k_transpose_w<<<dim3(16, 112),  256, 0, stream>>>(Wk, WkT, 3584, 512);
    k_transpose_w<<<dim3(16, 112),  256, 0, stream>>>(Wv, WvT, 3584, 512);
    k_transpose_w<<<dim3(112, 112), 256, 0, stream>>>(Wo, WoT, 3584, 3584);

    k_gemm_qkv<<<dim3(36, 16), 256, 0, stream>>>(Xb, WqT, WkT, WvT, Qb, Kb, Vb);
    k_rope<<<dim3(512), 256, 0, stream>>>(Qb, Kb, pos);
    k_transpose_v<<<dim3(16, 64), 256, 0, stream>>>(Vb, Vt);
    k_flash<<<dim3(28, 16), 256, 0, stream>>>(Qb, Kb, Vt, At);
    k_gemm_o<<<dim3(28, 16), 256, 0, stream>>>(At, WoT, out);
}

// Round 3
// 479.463 us; speedup vs baseline: 1.3430x; 1.1336x over previous
//
#include <hip/hip_runtime.h>
#include <cstdint>
#include <cstddef>

typedef __bf16 bf16x8 __attribute__((ext_vector_type(8)));
typedef float f32x4 __attribute__((ext_vector_type(4)));

__device__ __forceinline__ uint16_t f2bf(float f) {
    union { float f; uint32_t u; } v; v.f = f;
    uint32_t r = (v.u + 0x7fffu + ((v.u >> 16) & 1u)) >> 16;
    return (uint16_t)r;
}
__device__ __forceinline__ float bf2f(uint16_t h) {
    union { uint32_t u; float f; } v; v.u = ((uint32_t)h) << 16;
    return v.f;
}

// DPP cross-lane move within rows of 16 lanes (VALU, no LDS)
template <int CTRL>
__device__ __forceinline__ float dppf(float x) {
    union { float f; int i; } a; a.f = x;
    union { int i; float f; } b;
    b.i = __builtin_amdgcn_update_dpp(a.i, a.i, CTRL, 0xf, 0xf, false);
    return b.f;
}
// full 16-lane reductions via row_ror (0x120+N)
__device__ __forceinline__ float rmax16(float x) {
    x = fmaxf(x, dppf<0x128>(x));
    x = fmaxf(x, dppf<0x124>(x));
    x = fmaxf(x, dppf<0x122>(x));
    x = fmaxf(x, dppf<0x121>(x));
    return x;
}
__device__ __forceinline__ float radd16(float x) {
    x += dppf<0x128>(x);
    x += dppf<0x124>(x);
    x += dppf<0x122>(x);
    x += dppf<0x121>(x);
    return x;
}

// async 16B/lane global->LDS (wave-uniform LDS base; HW scatters lane i at +16i)
__device__ __forceinline__ void gload_lds16(const void* g, void* l) {
    __builtin_amdgcn_global_load_lds(
        (__attribute__((address_space(1))) void*)g,
        (__attribute__((address_space(3))) void*)l, 16, 0, 0);
}

// ---------------------------------------------------------------------------
// hidden fp32 -> bf16
// ---------------------------------------------------------------------------
__global__ __launch_bounds__(256) void k_tobf16(const float* __restrict__ X,
                                                uint16_t* __restrict__ Y) {
    int i = (blockIdx.x * 256 + threadIdx.x) * 4;
    f32x4 v = *reinterpret_cast<const f32x4*>(X + i);
    uint2 o;
    o.x = (uint32_t)f2bf(v[0]) | ((uint32_t)f2bf(v[1]) << 16);
    o.y = (uint32_t)f2bf(v[2]) | ((uint32_t)f2bf(v[3]) << 16);
    *reinterpret_cast<uint2*>(Y + i) = o;
}

// ---------------------------------------------------------------------------
// Weight transpose + convert: W (R x C, fp32) -> Wt (C x R, bf16)
// ---------------------------------------------------------------------------
__global__ __launch_bounds__(256) void k_transpose_w(const float* __restrict__ W,
                                                     uint16_t* __restrict__ Wt,
                                                     int R, int C) {
    __shared__ uint16_t tile[32][33];
    int c0 = blockIdx.x * 32;
    int r0 = blockIdx.y * 32;
    int t = threadIdx.x;
    int tc = t & 31, tr = t >> 5;
#pragma unroll
    for (int i = 0; i < 4; ++i) {
        int r = tr * 4 + i;
        tile[r][tc] = f2bf(W[(size_t)(r0 + r) * C + c0 + tc]);
    }
    __syncthreads();
#pragma unroll
    for (int i = 0; i < 4; ++i) {
        int c = tr * 4 + i;
        Wt[(size_t)(c0 + c) * R + r0 + tc] = tile[tc][c];
    }
}

// ---------------------------------------------------------------------------
// V transpose: V (2048 x 512 bf16) -> Vt (4 x 128 x 2048 bf16)
// ---------------------------------------------------------------------------
__global__ __launch_bounds__(256) void k_transpose_v(const uint16_t* __restrict__ V,
                                                     uint16_t* __restrict__ Vt) {
    __shared__ uint16_t tile[32][33];
    int c0 = blockIdx.x * 32;
    int s0 = blockIdx.y * 32;
    int t = threadIdx.x;
    int tc = t & 31, tr = t >> 5;
#pragma unroll
    for (int i = 0; i < 4; ++i) {
        int s = tr * 4 + i;
        tile[s][tc] = V[(size_t)(s0 + s) * 512 + c0 + tc];
    }
    __syncthreads();
#pragma unroll
    for (int i = 0; i < 4; ++i) {
        int c = c0 + tr * 4 + i;
        Vt[(size_t)c * 2048 + s0 + tc] = tile[tc][tr * 4 + i];
    }
}

// ---------------------------------------------------------------------------
// RoPE in place. Q scaled by (1/sqrt(128))*log2(e) for exp2-domain softmax.
// ---------------------------------------------------------------------------
__global__ __launch_bounds__(256) void k_rope(uint16_t* __restrict__ Q,
                                              uint16_t* __restrict__ K,
                                              const int* __restrict__ pos_ids) {
    int idx = blockIdx.x * 256 + threadIdx.x;
    int d = idx & 63;
    int s = idx >> 6;
    float pos = (float)pos_ids[s];
    float ang = pos * exp2f((float)d * (-19.931568569324174f / 64.0f));
    float cs = cosf(ang), sn = sinf(ang);
    const float qscale = 0.08838834764831845f * 1.4426950408889634f;
    uint16_t* q = Q + (size_t)s * 3584 + d;
#pragma unroll
    for (int h = 0; h < 28; ++h) {
        float x1 = bf2f(q[h * 128]);
        float x2 = bf2f(q[h * 128 + 64]);
        q[h * 128]      = f2bf((x1 * cs - x2 * sn) * qscale);
        q[h * 128 + 64] = f2bf((x2 * cs + x1 * sn) * qscale);
    }
    uint16_t* k = K + (size_t)s * 512 + d;
#pragma unroll
    for (int h = 0; h < 4; ++h) {
        float x1 = bf2f(k[h * 128]);
        float x2 = bf2f(k[h * 128 + 64]);
        k[h * 128]      = f2bf(x1 * cs - x2 * sn);
        k[h * 128 + 64] = f2bf(x2 * cs + x1 * sn);
    }
}

// ---------------------------------------------------------------------------
// m97-style GEMM: 128x128 tile, BK=32, global_load_lds width-16 staging.
// ---------------------------------------------------------------------------
#define BK 32

__global__ __launch_bounds__(256) void k_gemm_qkv(
    const uint16_t* __restrict__ A,
    const uint16_t* __restrict__ WqT,
    const uint16_t* __restrict__ WkT,
    const uint16_t* __restrict__ WvT,
    uint16_t* __restrict__ Q,
    uint16_t* __restrict__ K,
    uint16_t* __restrict__ V)
{
    __shared__ uint16_t Als[128 * BK];
    __shared__ uint16_t Bls[128 * BK];

    int nt = blockIdx.x;
    int m0 = blockIdx.y * 128;

    const uint16_t* Bt; uint16_t* dst; int dstStride; int colBase;
    if (nt < 28)      { Bt = WqT + (size_t)nt * 128 * 3584;        dst = Q; dstStride = 3584; colBase = nt * 128; }
    else if (nt < 32) { Bt = WkT + (size_t)(nt - 28) * 128 * 3584; dst = K; dstStride = 512;  colBase = (nt - 28) * 128; }
    else              { Bt = WvT + (size_t)(nt - 32) * 128 * 3584; dst = V; dstStride = 512;  colBase = (nt - 32) * 128; }

    int tid = threadIdx.x;
    int w = tid >> 6, lane = tid & 63, quad = lane >> 4, l15 = lane & 15;
    int wm = (w >> 1) * 64, wn = (w & 1) * 64;

    int lrow = lane >> 2;
    int lcol = (lane & 3) * 8;

    const uint16_t* aS = A  + (size_t)(m0 + w * 32 + lrow) * 3584 + lcol;
    const uint16_t* bS = Bt + (size_t)(w * 32 + lrow) * 3584 + lcol;
    uint16_t* aD0 = &Als[(w * 32) * BK];
    uint16_t* aD1 = &Als[(w * 32 + 16) * BK];
    uint16_t* bD0 = &Bls[(w * 32) * BK];
    uint16_t* bD1 = &Bls[(w * 32 + 16) * BK];

    f32x4 acc[4][4] = {};

    for (int k0 = 0; k0 < 3584; k0 += BK) {
        __syncthreads();
        gload_lds16(aS + k0, aD0);
        gload_lds16(aS + k0 + (size_t)16 * 3584, aD1);
        gload_lds16(bS + k0, bD0);
        gload_lds16(bS + k0 + (size_t)16 * 3584, bD1);
        __syncthreads();

        bf16x8 af[4], bfr[4];
#pragma unroll
        for (int i = 0; i < 4; ++i)
            af[i] = *reinterpret_cast<const bf16x8*>(&Als[(wm + i * 16 + l15) * BK + quad * 8]);
#pragma unroll
        for (int j = 0; j < 4; ++j)
            bfr[j] = *reinterpret_cast<const bf16x8*>(&Bls[(wn + j * 16 + l15) * BK + quad * 8]);
#pragma unroll
        for (int i = 0; i < 4; ++i)
#pragma unroll
            for (int j = 0; j < 4; ++j)
                acc[i][j] = __builtin_amdgcn_mfma_f32_16x16x32_bf16(af[i], bfr[j], acc[i][j], 0, 0, 0);
    }

#pragma unroll
    for (int i = 0; i < 4; ++i)
#pragma unroll
        for (int r = 0; r < 4; ++r) {
            int grow = m0 + wm + i * 16 + quad * 4 + r;
#pragma unroll
            for (int j = 0; j < 4; ++j) {
                int gcol = colBase + wn + j * 16 + l15;
                dst[(size_t)grow * dstStride + gcol] = f2bf(acc[i][j][r]);
            }
        }
}

__global__ __launch_bounds__(256) void k_gemm_o(
    const uint16_t* __restrict__ A,
    const uint16_t* __restrict__ WoT,
    float* __restrict__ out)
{
    __shared__ uint16_t Als[128 * BK];
    __shared__ uint16_t Bls[128 * BK];

    int nt = blockIdx.x;
    int m0 = blockIdx.y * 128;
    const uint16_t* Bt = WoT + (size_t)nt * 128 * 3584;

    int tid = threadIdx.x;
    int w = tid >> 6, lane = tid & 63, quad = lane >> 4, l15 = lane & 15;
    int wm = (w >> 1) * 64, wn = (w & 1) * 64;

    int lrow = lane >> 2;
    int lcol = (lane & 3) * 8;

    const uint16_t* aS = A  + (size_t)(m0 + w * 32 + lrow) * 3584 + lcol;
    const uint16_t* bS = Bt + (size_t)(w * 32 + lrow) * 3584 + lcol;
    uint16_t* aD0 = &Als[(w * 32) * BK];
    uint16_t* aD1 = &Als[(w * 32 + 16) * BK];
    uint16_t* bD0 = &Bls[(w * 32) * BK];
    uint16_t* bD1 = &Bls[(w * 32 + 16) * BK];

    f32x4 acc[4][4] = {};

    for (int k0 = 0; k0 < 3584; k0 += BK) {
        __syncthreads();
        gload_lds16(aS + k0, aD0);
        gload_lds16(aS + k0 + (size_t)16 * 3584, aD1);
        gload_lds16(bS + k0, bD0);
        gload_lds16(bS + k0 + (size_t)16 * 3584, bD1);
        __syncthreads();

        bf16x8 af[4], bfr[4];
#pragma unroll
        for (int i = 0; i < 4; ++i)
            af[i] = *reinterpret_cast<const bf16x8*>(&Als[(wm + i * 16 + l15) * BK + quad * 8]);
#pragma unroll
        for (int j = 0; j < 4; ++j)
            bfr[j] = *reinterpret_cast<const bf16x8*>(&Bls[(wn + j * 16 + l15) * BK + quad * 8]);
#pragma unroll
        for (int i = 0; i < 4; ++i)
#pragma unroll
            for (int j = 0; j < 4; ++j)
                acc[i][j] = __builtin_amdgcn_mfma_f32_16x16x32_bf16(af[i], bfr[j], acc[i][j], 0, 0, 0);
    }

#pragma unroll
    for (int i = 0; i < 4; ++i)
#pragma unroll
        for (int r = 0; r < 4; ++r) {
            int grow = m0 + wm + i * 16 + quad * 4 + r;
#pragma unroll
            for (int j = 0; j < 4; ++j) {
                int gcol = nt * 128 + wn + j * 16 + l15;
                out[(size_t)grow * 3584 + gcol] = acc[i][j][r];
            }
        }
}

// ---------------------------------------------------------------------------
// Flash attention, split-K within block.
// Block = 4 waves over the SAME 32 q rows; wave w owns key-tiles {w, w+4, ...}
// of 32 keys. No barriers in the main loop; single barrier + LDS combine of
// the 4 partials at the end. K/V direct from global (L2-resident), K frags
// prefetched one tile ahead, V frags issued at tile top. DPP reductions.
// ---------------------------------------------------------------------------
#define FPLD 40

__global__ __launch_bounds__(256, 2) void k_flash(
    const uint16_t* __restrict__ Q,    // 2048x3584 (roped, *1/sqrt(d)*log2e)
    const uint16_t* __restrict__ K,    // 2048x512  (roped)
    const uint16_t* __restrict__ Vt,   // 4x128x2048
    uint16_t* __restrict__ O)          // 2048x3584
{
    __shared__ uint16_t Pls[4][32 * FPLD];
    __shared__ uint16_t AccS[4][32 * 128];
    __shared__ float    Ml[4][32][2];

    int h  = blockIdx.x;               // 0..27
    int qb = 63 - (int)blockIdx.y;     // heavy first
    int kvh = h / 7;
    int tid = threadIdx.x;
    int w = tid >> 6, lane = tid & 63, quad = lane >> 4, l15 = lane & 15;
    int q0 = qb * 32;

    const uint16_t* Kh = K + kvh * 128;
    const uint16_t* Vh = Vt + (size_t)kvh * 128 * 2048;
    uint16_t* Pw = &Pls[w][0];

    // Q fragments: 32 rows (2 x 16), A-layout
    bf16x8 qf[2][4];
#pragma unroll
    for (int s = 0; s < 2; ++s) {
        const uint16_t* qp = Q + (size_t)(q0 + s * 16 + l15) * 3584 + h * 128 + quad * 8;
#pragma unroll
        for (int c = 0; c < 4; ++c)
            qf[s][c] = *reinterpret_cast<const bf16x8*>(qp + c * 32);
    }

    f32x4 acc[2][8] = {};
    float m_i[2][4], l_i[2][4];
#pragma unroll
    for (int s = 0; s < 2; ++s)
#pragma unroll
        for (int r = 0; r < 4; ++r) { m_i[s][r] = -1e30f; l_i[s][r] = 0.f; }

    int tmax = qb;                     // tiles 0..qb (32 keys each)
    bf16x8 kf[8];
    int t = w;
    if (t <= tmax) {                   // prefetch first owned K tile
        const uint16_t* kp = Kh + (size_t)(t * 32 + l15) * 512 + quad * 8;
#pragma unroll
        for (int nt = 0; nt < 2; ++nt)
#pragma unroll
            for (int c = 0; c < 4; ++c)
                kf[nt * 4 + c] = *reinterpret_cast<const bf16x8*>(kp + (size_t)nt * 16 * 512 + c * 32);
    }

    for (; t <= tmax; t += 4) {
        int kb = t * 32;
        // V frags issued now, consumed after softmax (latency hidden)
        bf16x8 vf[8];
        const uint16_t* vp = Vh + (size_t)l15 * 2048 + kb + quad * 8;
#pragma unroll
        for (int dt = 0; dt < 8; ++dt)
            vf[dt] = *reinterpret_cast<const bf16x8*>(vp + (size_t)dt * 16 * 2048);

        // QK^T: 32 q x 32 keys
        f32x4 sc[2][2] = {};
#pragma unroll
        for (int nt = 0; nt < 2; ++nt)
#pragma unroll
            for (int c = 0; c < 4; ++c) {
                sc[0][nt] = __builtin_amdgcn_mfma_f32_16x16x32_bf16(qf[0][c], kf[nt * 4 + c], sc[0][nt], 0, 0, 0);
                sc[1][nt] = __builtin_amdgcn_mfma_f32_16x16x32_bf16(qf[1][c], kf[nt * 4 + c], sc[1][nt], 0, 0, 0);
            }

        // prefetch next owned K tile (hidden under softmax + PV)
        int tn = t + 4;
        if (tn <= tmax) {
            const uint16_t* kp = Kh + (size_t)(tn * 32 + l15) * 512 + quad * 8;
#pragma unroll
            for (int nt = 0; nt < 2; ++nt)
#pragma unroll
                for (int c = 0; c < 4; ++c)
                    kf[nt * 4 + c] = *reinterpret_cast<const bf16x8*>(kp + (size_t)nt * 16 * 512 + c * 32);
        }

        // causal mask (only possible on the last tile: kb+31 > q0)
        if (kb + 31 > q0) {
#pragma unroll
            for (int s = 0; s < 2; ++s)
#pragma unroll
                for (int nt = 0; nt < 2; ++nt) {
                    int key = kb + nt * 16 + l15;
#pragma unroll
                    for (int r = 0; r < 4; ++r) {
                        int row = q0 + s * 16 + quad * 4 + r;
                        if (key > row) sc[s][nt][r] = -1e30f;
                    }
                }
        }

        // online softmax (exp2 domain, DPP reductions)
#pragma unroll
        for (int s = 0; s < 2; ++s) {
            f32x4 alf;
#pragma unroll
            for (int r = 0; r < 4; ++r) {
                float mx = rmax16(fmaxf(sc[s][0][r], sc[s][1][r]));
                float mn = fmaxf(m_i[s][r], mx);
                alf[r] = __builtin_amdgcn_exp2f(m_i[s][r] - mn);
                m_i[s][r] = mn;
            }
#pragma unroll
            for (int r = 0; r < 4; ++r) {
                float p0 = __builtin_amdgcn_exp2f(sc[s][0][r] - m_i[s][r]);
                float p1 = __builtin_amdgcn_exp2f(sc[s][1][r] - m_i[s][r]);
                sc[s][0][r] = p0;
                sc[s][1][r] = p1;
                float rs = radd16(p0 + p1);
                l_i[s][r] = l_i[s][r] * alf[r] + rs;
            }
#pragma unroll
            for (int dt = 0; dt < 8; ++dt)
                acc[s][dt] *= alf;
#pragma unroll
            for (int nt = 0; nt < 2; ++nt)
#pragma unroll
                for (int r = 0; r < 4; ++r)
                    Pw[(s * 16 + quad * 4 + r) * FPLD + nt * 16 + l15] = f2bf(sc[s][nt][r]);
        }

        // PV: 32 q x 128 d over 32 keys (wave-private LDS, in-wave ordering)
        bf16x8 pf0 = *reinterpret_cast<const bf16x8*>(&Pw[l15 * FPLD + quad * 8]);
        bf16x8 pf1 = *reinterpret_cast<const bf16x8*>(&Pw[(16 + l15) * FPLD + quad * 8]);
#pragma unroll
        for (int dt = 0; dt < 8; ++dt) {
            acc[0][dt] = __builtin_amdgcn_mfma_f32_16x16x32_bf16(pf0, vf[dt], acc[0][dt], 0, 0, 0);
            acc[1][dt] = __builtin_amdgcn_mfma_f32_16x16x32_bf16(pf1, vf[dt], acc[1][dt], 0, 0, 0);
        }
    }

    // ---- write partials and combine across the 4 waves ----
    uint16_t* As = &AccS[w][0];
#pragma unroll
    for (int s = 0; s < 2; ++s)
#pragma unroll
        for (int dt = 0; dt < 8; ++dt)
#pragma unroll
            for (int r = 0; r < 4; ++r)
                As[(s * 16 + quad * 4 + r) * 128 + dt * 16 + l15] = f2bf(acc[s][dt][r]);
    if (l15 == 0) {
#pragma unroll
        for (int s = 0; s < 2; ++s)
#pragma unroll
            for (int r = 0; r < 4; ++r) {
                Ml[w][s * 16 + quad * 4 + r][0] = m_i[s][r];
                Ml[w][s * 16 + quad * 4 + r][1] = l_i[s][r];
            }
    }
    __syncthreads();

    // combine: wave w handles rows w*8..w*8+7; lane -> (row, 16-col chunk)
    {
        int rowl = w * 8 + (lane >> 3);
        int c16 = (lane & 7) * 16;
        float m0 = Ml[0][rowl][0], m1 = Ml[1][rowl][0], m2 = Ml[2][rowl][0], m3 = Ml[3][rowl][0];
        float M = fmaxf(fmaxf(m0, m1), fmaxf(m2, m3));
        float s0 = __builtin_amdgcn_exp2f(m0 - M);
        float s1 = __builtin_amdgcn_exp2f(m1 - M);
        float s2 = __builtin_amdgcn_exp2f(m2 - M);
        float s3 = __builtin_amdgcn_exp2f(m3 - M);
        float lt = Ml[0][rowl][1] * s0 + Ml[1][rowl][1] * s1 +
                   Ml[2][rowl][1] * s2 + Ml[3][rowl][1] * s3;
        float inv = __builtin_amdgcn_rcpf(lt);
        float sw[4] = {s0, s1, s2, s3};

        float o[16];
#pragma unroll
        for (int j = 0; j < 16; ++j) o[j] = 0.f;
#pragma unroll
        for (int sl = 0; sl < 4; ++sl) {
            const uint16_t* src = &AccS[sl][rowl * 128 + c16];
            float ssc = sw[sl];
#pragma unroll
            for (int j = 0; j < 16; ++j)
                o[j] += bf2f(src[j]) * ssc;
        }
        uint16_t ob[16];
#pragma unroll
        for (int j = 0; j < 16; ++j) ob[j] = f2bf(o[j] * inv);
        uint16_t* op = O + (size_t)(q0 + rowl) * 3584 + h * 128 + c16;
        *reinterpret_cast<uint4*>(op)     = *reinterpret_cast<uint4*>(&ob[0]);
        *reinterpret_cast<uint4*>(op + 8) = *reinterpret_cast<uint4*>(&ob[8]);
    }
}

// ---------------------------------------------------------------------------
extern "C" void kernel_launch(void* const* d_in, const int* in_sizes, int n_in,
                              void* d_out, int out_size, void* d_ws, size_t ws_size,
                              hipStream_t stream) {
    const float* hidden = (const float*)d_in[0];
    const int*   pos    = (const int*)d_in[1];
    const float* Wq     = (const float*)d_in[2];
    const float* Wk     = (const float*)d_in[3];
    const float* Wv     = (const float*)d_in[4];
    const float* Wo     = (const float*)d_in[5];
    float* out = (float*)d_out;

    char* ws = (char*)d_ws;
    size_t o = 0;
    uint16_t* WqT = (uint16_t*)(ws + o); o += (size_t)3584 * 3584 * 2;
    uint16_t* WkT = (uint16_t*)(ws + o); o += (size_t)512  * 3584 * 2;
    uint16_t* WvT = (uint16_t*)(ws + o); o += (size_t)512  * 3584 * 2;
    uint16_t* WoT = (uint16_t*)(ws + o); o += (size_t)3584 * 3584 * 2;
    uint16_t* Xb  = (uint16_t*)(ws + o); o += (size_t)2048 * 3584 * 2;  // aliased as At
    uint16_t* Qb  = (uint16_t*)(ws + o); o += (size_t)2048 * 3584 * 2;
    uint16_t* Kb  = (uint16_t*)(ws + o); o += (size_t)2048 * 512  * 2;
    uint16_t* Vb  = (uint16_t*)(ws + o); o += (size_t)2048 * 512  * 2;
    uint16_t* Vt  = (uint16_t*)(ws + o); o += (size_t)2048 * 512  * 2;
    uint16_t* At  = Xb;

    k_tobf16<<<dim3(7168), 256, 0, stream>>>(hidden, Xb);
    k_transpose_w<<<dim3(112, 112), 256, 0, stream>>>(Wq, WqT, 3584, 3584);
    k_transpose_w<<<dim3(16, 112),  256, 0, stream>>>(Wk, WkT, 3584, 512);
    k_transpose_w<<<dim3(16, 112),  256, 0, stream>>>(Wv, WvT, 3584, 512);
    k_transpose_w<<<dim3(112, 112), 256, 0, stream>>>(Wo, WoT, 3584, 3584);

    k_gemm_qkv<<<dim3(36, 16), 256, 0, stream>>>(Xb, WqT, WkT, WvT, Qb, Kb, Vb);
    k_rope<<<dim3(512), 256, 0, stream>>>(Qb, Kb, pos);
    k_transpose_v<<<dim3(16, 64), 256, 0, stream>>>(Vb, Vt);
    k_flash<<<dim3(28, 64), 256, 0, stream>>>(Qb, Kb, Vt, At);
    k_gemm_o<<<dim3(28, 16), 256, 0, stream>>>(At, WoT, out);
}